// Round 1
// baseline (181.205 us; speedup 1.0000x reference)
//
#include <hip/hip_runtime.h>

// FlowNetC correlation, B=8 C=256 H=64 W=128, 9x9 displacement grid.
// out[b, (i+4)*9+(j+4), h, w] = (1/256) * sum_c in1[b,c,h,w] * in2[b,c,h+i,w+j]
// (in2 zero-padded by 4 in h and w).
//
// Structure: 256 blocks (b x 2-row h-tile) x 576 threads (9 waves, wave = dy).
// Lane = (q in 0..15: 8 w-pixels, hp in 0..1: h row, cs in 0..1: channel half).
// Each lane: acc[8 px][9 dx] fp32, Q=8 window reuse -> 0.89 B LDS / FMA.
// in2 rows staged to LDS (parity-deinterleaved for conflict-free ds_read_b128)
// via global_load_lds with pre-swizzled per-lane source; triple-buffered with
// counted vmcnt + raw s_barrier. Channel halves reduced by shfl_xor(32).

#define AS1 __attribute__((address_space(1)))
#define AS3 __attribute__((address_space(3)))

namespace {

constexpr int Cc = 256, Hh = 64, Ww = 128;
constexpr int HW = Hh * Ww;          // 8192
constexpr int ND = 81;
constexpr int ROWS = 10;             // staged rows per (buf, ch-half)
constexpr int RSTRIDE = 136;         // floats per LDS row: 4 pad | 128 | 4 pad (deinterleaved)
constexpr int CHSTR = ROWS * RSTRIDE;  // 1360
constexpr int BUFSTR = 2 * CHSTR;      // 2720

__device__ __forceinline__ void async4(const float* g, float* l) {
  __builtin_amdgcn_global_load_lds((const AS1 unsigned int*)(g),
                                   (AS3 unsigned int*)(l), 4, 0, 0);
}

__global__ __launch_bounds__(576, 3) void corr_kernel(
    const float* __restrict__ in1, const float* __restrict__ in2,
    float* __restrict__ out) {
  __shared__ __align__(16) float lds[3 * BUFSTR];

  const int tid = threadIdx.x;
  const int dyw = tid >> 6;          // wave id = dy index 0..8
  const int lane = tid & 63;
  const int q = lane & 15;           // w-oct: pixels w = 8q..8q+7
  const int hp = (lane >> 4) & 1;    // h row within tile
  const int cs = lane >> 5;          // channel half

  const int bid = blockIdx.x;
  const int b = bid >> 5;
  const int h0 = (bid & 31) << 1;
  const bool bdry = (h0 < 4) || (h0 > 58);  // stages OOB rows -> uneven vmcnt

  // zero the x-pad blocks once (phys blocks 0 and 33 of each row; never rewritten)
  if (tid < 480) {
    int bufi = tid / 160, rem = tid - bufi * 160;
    int csx = rem / 80; rem -= csx * 80;
    int row = rem >> 3, sl = rem & 7;
    int slot = (sl < 4) ? sl : (128 + sl);
    lds[bufi * BUFSTR + csx * CHSTR + row * RSTRIDE + slot] = 0.0f;
  }
  __syncthreads();

  // staging: per iter, 40 units = (2 ch-halves x 10 rows x 2 halves-of-row),
  // 5 per wave (wave 8 duplicates units 0..4 benignly). Deinterleaved source x:
  const int sx0 = 8 * (lane >> 2) + (lane & 3) + 4;  // row-half 0 -> slots [4,68)
  const int sx1 = sx0 - 4;                           // row-half 1 -> slots [68,132)
  const size_t in2_b = (size_t)b * Cc * HW;

  int ldsoff[5]; int goff[5]; bool gval[5];
#pragma unroll
  for (int k = 0; k < 5; ++k) {
    int u = dyw * 5 + k; if (u >= 40) u -= 40;
    int cs_u = u / 20; int rem = u - cs_u * 20;
    int rr = rem >> 1; int half = rem & 1;
    int grow = h0 - 4 + rr;
    ldsoff[k] = cs_u * CHSTR + rr * RSTRIDE + 4 + 64 * half;
    goff[k] = cs_u * 128 * HW + grow * Ww + (half ? sx1 : sx0);
    gval[k] = (unsigned)grow < (unsigned)Hh;
  }

  auto stage = [&](int j) {  // j = channel index 0..127 (ch-half adds 128)
    const int bf = j % 3;
    const float* in2j = in2 + in2_b + (size_t)j * HW;
#pragma unroll
    for (int k = 0; k < 5; ++k) {
      float* ldst = &lds[bf * BUFSTR + ldsoff[k]];
      if (gval[k]) async4(in2j + goff[k], ldst);
      else         ldst[lane] = 0.0f;
    }
  };

  const float* in1p =
      in1 + ((size_t)(b * Cc + cs * 128) * Hh + (h0 + hp)) * Ww + 8 * q;

  float acc[8][9];
#pragma unroll
  for (int px = 0; px < 8; ++px)
#pragma unroll
    for (int dx = 0; dx < 9; ++dx) acc[px][dx] = 0.0f;

  float v1c[8], v1n[8];
  {
    float4 a = *(const float4*)(in1p);
    float4 c4 = *(const float4*)(in1p + 4);
    v1c[0] = a.x; v1c[1] = a.y; v1c[2] = a.z; v1c[3] = a.w;
    v1c[4] = c4.x; v1c[5] = c4.y; v1c[6] = c4.z; v1c[7] = c4.w;
  }
  stage(0);
  stage(1);
  if (!bdry) asm volatile("s_waitcnt vmcnt(5) lgkmcnt(0)" ::: "memory");
  else       asm volatile("s_waitcnt vmcnt(0) lgkmcnt(0)" ::: "memory");
  __builtin_amdgcn_s_barrier();
  __builtin_amdgcn_sched_barrier(0);

  const int rb_const = cs * CHSTR + (hp + dyw) * RSTRIDE;

  for (int i = 0; i < 128; ++i) {
    if (i + 1 < 128) {  // prefetch v1(i+1)
      const float* p = in1p + (size_t)(i + 1) * HW;
      float4 a = *(const float4*)(p);
      float4 c4 = *(const float4*)(p + 4);
      v1n[0] = a.x; v1n[1] = a.y; v1n[2] = a.z; v1n[3] = a.w;
      v1n[4] = c4.x; v1n[5] = c4.y; v1n[6] = c4.z; v1n[7] = c4.w;
    }
    if (i + 2 < 128) stage(i + 2);

    // compute iteration i from buffer i%3
    const int base = (i % 3) * BUFSTR + rb_const + 4 * q;
    const float4 W0 = *(const float4*)&lds[base];        // t 0..3   (x-block 2q)
    const float4 Wa = *(const float4*)&lds[base + 4];    // t 8..11  (x-block 2q+2)
    const float4 W2 = *(const float4*)&lds[base + 68];   // t 4..7   (x-block 2q+1)
    const float4 Wb = *(const float4*)&lds[base + 72];   // t 12..15 (x-block 2q+3)
    const float win[16] = {W0.x, W0.y, W0.z, W0.w, W2.x, W2.y, W2.z, W2.w,
                           Wa.x, Wa.y, Wa.z, Wa.w, Wb.x, Wb.y, Wb.z, Wb.w};
#pragma unroll
    for (int dx = 0; dx < 9; ++dx)
#pragma unroll
      for (int px = 0; px < 8; ++px)
        acc[px][dx] = fmaf(v1c[px], win[px + dx], acc[px][dx]);

#pragma unroll
    for (int px = 0; px < 8; ++px) v1c[px] = v1n[px];

    // drain stage(i+1) only; keep v1(i+1)+stage(i+2) in flight
    if (i < 126 && !bdry) {
      asm volatile("s_waitcnt vmcnt(7) lgkmcnt(0)" ::: "memory");
    } else {
      asm volatile("s_waitcnt vmcnt(0) lgkmcnt(0)" ::: "memory");
    }
    __builtin_amdgcn_s_barrier();
    __builtin_amdgcn_sched_barrier(0);
  }

  // reduce channel halves
#pragma unroll
  for (int px = 0; px < 8; ++px)
#pragma unroll
    for (int dx = 0; dx < 9; ++dx)
      acc[px][dx] += __shfl_xor(acc[px][dx], 32, 64);

  const float s = 1.0f / 256.0f;
  float* outp =
      out + (((size_t)b * ND + (size_t)dyw * 9) * Hh + (h0 + hp)) * Ww + 8 * q;
  if (cs == 0) {
#pragma unroll
    for (int dx = 0; dx < 5; ++dx) {
      float4 lo = make_float4(acc[0][dx] * s, acc[1][dx] * s, acc[2][dx] * s,
                              acc[3][dx] * s);
      float4 hi = make_float4(acc[4][dx] * s, acc[5][dx] * s, acc[6][dx] * s,
                              acc[7][dx] * s);
      *(float4*)(outp + (size_t)dx * HW) = lo;
      *(float4*)(outp + (size_t)dx * HW + 4) = hi;
    }
  } else {
#pragma unroll
    for (int dx = 4; dx < 9; ++dx) {  // dx=4 duplicated with identical value
      float4 lo = make_float4(acc[0][dx] * s, acc[1][dx] * s, acc[2][dx] * s,
                              acc[3][dx] * s);
      float4 hi = make_float4(acc[4][dx] * s, acc[5][dx] * s, acc[6][dx] * s,
                              acc[7][dx] * s);
      *(float4*)(outp + (size_t)dx * HW) = lo;
      *(float4*)(outp + (size_t)dx * HW + 4) = hi;
    }
  }
}

}  // namespace

extern "C" void kernel_launch(void* const* d_in, const int* in_sizes, int n_in,
                              void* d_out, int out_size, void* d_ws,
                              size_t ws_size, hipStream_t stream) {
  (void)in_sizes; (void)n_in; (void)out_size; (void)d_ws; (void)ws_size;
  const float* in1 = (const float*)d_in[0];
  const float* in2 = (const float*)d_in[1];
  float* outp = (float*)d_out;
  corr_kernel<<<256, 576, 0, stream>>>(in1, in2, outp);
}